// Round 10
// baseline (175.595 us; speedup 1.0000x reference)
//
#include <hip/hip_runtime.h>
#include <stdint.h>

#define N_IMG 8
#define NCLS  80
#define HW    10000
#define HW4   (HW/4)
#define PER   (NCLS*HW)      /* 800000 per image */
#define L1B   4096           /* level-1 buckets: score bits 30:19 */
#define L2B   8192           /* level-2 buckets: score bits 18:6  */
#define TOPK  1000
#define CAP   2048           /* superset cap (skip-refine path guarantees <= CAP) */
#define KEEP  100
#define MROW  1024
#define CCAP  131072         /* candidate buffer cap per image (~117k expected) */
#define SCAP  4096           /* per-block LDS candidate staging cap (~1456 expected) */
#define GATE  (-3.0f)        /* sigmoid(-3.0)=0.04743 < 0.05: safe pre-gate */
#define PRE_TH 0.05f
#define NMS_TH 0.6f
#define CLS_OFF 4096.0f

/* meta layout: one 64B line per image, meta[n*16 + k]:
   k=0 B1, k=1 need, k=2 B2, k=3 cnt1, k=4 cnt2, k=5 skip_refine_flag */
#define MSTR 16

__device__ __forceinline__ float sigf(float x) {
    return 1.0f / (1.0f + expf(-x));
}

// ---------------- pass 0: sigmoid(centerness) + zero hists/meta (replaces memset) ----------------
__global__ __launch_bounds__(256) void k_prep(const float* __restrict__ bctr,
                                              float* __restrict__ sct,
                                              uint32_t* __restrict__ h1,
                                              uint32_t* __restrict__ h2,
                                              int* __restrict__ meta) {
    const int gid = blockIdx.x * 256 + threadIdx.x;
    const int gsz = gridDim.x * 256;
    for (int i = gid; i < N_IMG * HW; i += gsz) sct[i] = sigf(bctr[i]);
    for (int i = gid; i < N_IMG * L1B; i += gsz) h1[i] = 0;
    for (int i = gid; i < N_IMG * L2B; i += gsz) h2[i] = 0;
    if (gid < N_IMG * MSTR) meta[gid] = 0;
}

// ---------------- pass 1: gated select — LDS histogram + LDS-staged compaction ----------------
template<bool BIG>
__global__ __launch_bounds__(256) void k_select(const float* __restrict__ bcls,
                                                const float* __restrict__ sct,
                                                uint32_t* __restrict__ h1,
                                                int* __restrict__ meta,
                                                uint64_t* __restrict__ cand) {
    __shared__ uint32_t h[L1B];      // 16KB LDS histogram
    __shared__ uint64_t sbuf[SCAP];  // 32KB LDS candidate staging
    __shared__ int scnt, sbase;
    const int c = blockIdx.x, n = blockIdx.y;
    const int tid = threadIdx.x;
    const int ln = tid & 63;
    for (int b = tid; b < L1B; b += 256) h[b] = 0;
    if (tid == 0) scnt = 0;
    __syncthreads();

    const float4* row = (const float4*)(bcls + ((size_t)n * NCLS + c) * HW);
    const float4* sr  = (const float4*)(sct + (size_t)n * HW);
    uint64_t* cb = cand + (size_t)n * CCAP;
    int* cnt1 = &meta[n * MSTR + 3];
    for (int v = tid; v < HW4; v += 256) {
        float4 x = row[v];
        if (x.x > GATE || x.y > GATE || x.z > GATE || x.w > GATE) {
            float4 t = sr[v];
            float xs[4] = {x.x, x.y, x.z, x.w};
            float ts[4] = {t.x, t.y, t.z, t.w};
            #pragma unroll
            for (int k = 0; k < 4; ++k) {
                if (xs[k] > GATE) {
                    float cl = sigf(xs[k]);
                    if (cl > PRE_TH) {
                        uint32_t u = __float_as_uint(cl * ts[k]);
                        atomicAdd(&h[u >> 19], 1u);                   // LDS atomic (spread buckets)
                        if (BIG) {
                            uint32_t f = (uint32_t)((4 * v + k) * NCLS + c);
                            uint64_t rec = ((uint64_t)u << 32) | (uint64_t)(0xFFFFFFFFu - f);
                            // wave-aggregated reservation: one LDS atomic per wave-group
                            uint64_t mb = __ballot(1);
                            int prefix = __popcll(mb & ((1ull << ln) - 1ull));
                            int leader = __ffsll((unsigned long long)mb) - 1;
                            int base = 0;
                            if (ln == leader) base = atomicAdd(&scnt, (int)__popcll(mb));
                            base = __shfl(base, leader, 64);
                            int pos = base + prefix;
                            if (pos < SCAP) sbuf[pos] = rec;
                            else {                                    // statistical overflow path
                                int g = atomicAdd(cnt1, 1);
                                if (g < CCAP) cb[g] = rec;
                            }
                        }
                    }
                }
            }
        }
    }
    __syncthreads();

    // merge LDS histogram (sparse: ~160 nonzero buckets)
    uint32_t* gh = h1 + n * L1B;
    for (int b = tid; b < L1B; b += 256)
        if (h[b]) atomicAdd(&gh[b], h[b]);

    // bulk-reserve one chunk per block, coalesced flush
    if (BIG) {
        int cc = (scnt < SCAP) ? scnt : SCAP;
        if (tid == 0) sbase = atomicAdd(cnt1, cc);
        __syncthreads();
        for (int i = tid; i < cc; i += 256) {
            int g = sbase + i;
            if (g < CCAP) cb[g] = sbuf[i];
        }
    }
}

// ---------------- scan 1: level-1 boundary bucket + skip-refine decision ----------------
__global__ __launch_bounds__(256) void k_scan1(const uint32_t* __restrict__ hist,
                                               int* __restrict__ meta) {
    __shared__ uint32_t csum[256];
    const int n = blockIdx.x;
    const uint32_t* h = hist + n * L1B;
    const int t = threadIdx.x;
    uint32_t s = 0;
    for (int b = t * 16; b < t * 16 + 16; ++b) s += h[b];
    csum[t] = s;
    __syncthreads();
    if (t == 0) {
        long long acc = 0;
        int b1 = -1;
        for (int c = 255; c >= 0; --c) {
            if (acc + (long long)csum[c] >= TOPK) {
                for (int b = c * 16 + 15; b >= c * 16; --b) {
                    if (acc + (long long)h[b] >= TOPK) { b1 = b; break; }
                    acc += h[b];
                }
                break;
            }
            acc += csum[c];
        }
        int flag, nee;
        if (b1 < 0) {                       // fewer than TOPK candidates: take all
            b1 = 0; nee = 0; flag = 1;
        } else {
            nee = TOPK - (int)acc;
            flag = (acc + (long long)h[b1] <= CAP) ? 1 : 0;   // superset fits: skip L2 refine
        }
        meta[n * MSTR + 0] = b1;
        meta[n * MSTR + 1] = nee;
        if (flag) meta[n * MSTR + 2] = 0;   // B2 = 0 -> take whole boundary bucket
        meta[n * MSTR + 5] = flag;
    }
}

// ---------------- pass 2 (candbuf): L2 histogram inside boundary bucket ----------------
__global__ __launch_bounds__(256) void k_refine_cand(const uint64_t* __restrict__ cand,
                                                     const int* __restrict__ meta,
                                                     uint32_t* __restrict__ h2) {
    const int n = blockIdx.y;
    if (meta[n * MSTR + 5]) return;         // skip-refine fast path
    int cn = meta[n * MSTR + 3]; if (cn > CCAP) cn = CCAP;
    const int b1 = meta[n * MSTR + 0];
    const uint64_t* cb = cand + (size_t)n * CCAP;
    uint32_t* h = h2 + n * L2B;
    const int stride = gridDim.x * blockDim.x;
    for (int i = blockIdx.x * blockDim.x + threadIdx.x; i < cn; i += stride) {
        uint32_t u = (uint32_t)(cb[i] >> 32);
        if ((int)(u >> 19) == b1) atomicAdd(&h[(u >> 6) & (L2B - 1)], 1u);
    }
}

// ---------------- pass 2 (fallback): gated full-tensor L2 histogram ----------------
__global__ __launch_bounds__(256) void k_refine_full(const float* __restrict__ bcls,
                                                     const float* __restrict__ sct,
                                                     const int* __restrict__ meta,
                                                     uint32_t* __restrict__ h2) {
    const int c = blockIdx.x, n = blockIdx.y;
    if (meta[n * MSTR + 5]) return;         // skip-refine fast path
    const int b1 = meta[n * MSTR + 0];
    const float4* row = (const float4*)(bcls + ((size_t)n * NCLS + c) * HW);
    const float4* sr  = (const float4*)(sct + (size_t)n * HW);
    uint32_t* h = h2 + n * L2B;
    for (int v = threadIdx.x; v < HW4; v += 256) {
        float4 x = row[v];
        if (x.x > GATE || x.y > GATE || x.z > GATE || x.w > GATE) {
            float4 t = sr[v];
            float xs[4] = {x.x, x.y, x.z, x.w};
            float ts[4] = {t.x, t.y, t.z, t.w};
            #pragma unroll
            for (int k = 0; k < 4; ++k) {
                if (xs[k] > GATE) {
                    float cl = sigf(xs[k]);
                    if (cl > PRE_TH) {
                        uint32_t u = __float_as_uint(cl * ts[k]);
                        if ((int)(u >> 19) == b1)
                            atomicAdd(&h[(u >> 6) & (L2B - 1)], 1u);
                    }
                }
            }
        }
    }
}

// ---------------- scan 2: level-2 boundary sub-bucket ----------------
__global__ __launch_bounds__(256) void k_scan2(const uint32_t* __restrict__ hist2,
                                               int* __restrict__ meta) {
    __shared__ uint32_t csum[256];
    const int n = blockIdx.x;
    if (meta[n * MSTR + 5]) return;         // skip-refine fast path (B2 stays 0 / unused)
    const uint32_t* h = hist2 + n * L2B;
    const long long target = meta[n * MSTR + 1];
    const int t = threadIdx.x;
    uint32_t s = 0;
    for (int b = t * 32; b < t * 32 + 32; ++b) s += h[b];
    csum[t] = s;
    __syncthreads();
    if (t == 0) {
        long long acc = 0;
        int b2 = 0;
        bool found = false;
        for (int c = 255; c >= 0 && !found; --c) {
            if (acc + (long long)csum[c] >= target) {
                for (int b = c * 32 + 31; b >= c * 32; --b) {
                    if (acc + (long long)h[b] >= target) { b2 = b; found = true; break; }
                    acc += h[b];
                }
            } else {
                acc += csum[c];
            }
        }
        meta[n * MSTR + 2] = b2;
    }
}

// ---------------- pass 3 (candbuf): final compaction, LDS-staged ----------------
__global__ __launch_bounds__(256) void k_compact_cand(const uint64_t* __restrict__ cand,
                                                      int* __restrict__ meta,
                                                      uint64_t* __restrict__ keys) {
    __shared__ uint64_t sb[CAP];            // 16KB winner staging
    __shared__ int sc, sb0;
    const int n = blockIdx.y;
    const int tid = threadIdx.x;
    int cn = meta[n * MSTR + 3]; if (cn > CCAP) cn = CCAP;
    const int b1 = meta[n * MSTR + 0], b2 = meta[n * MSTR + 2];
    const uint64_t* cb = cand + (size_t)n * CCAP;
    uint64_t* kk = keys + (size_t)n * CAP;
    if (tid == 0) sc = 0;
    __syncthreads();
    const int stride = gridDim.x * blockDim.x;
    for (int i = blockIdx.x * blockDim.x + tid; i < cn; i += stride) {
        uint64_t rec = cb[i];
        uint32_t u = (uint32_t)(rec >> 32);
        int e1 = (int)(u >> 19);
        int e2 = (int)((u >> 6) & (L2B - 1));
        if (e1 > b1 || (e1 == b1 && e2 >= b2)) {
            int pos = atomicAdd(&sc, 1);    // LDS atomic
            if (pos < CAP) sb[pos] = rec;
        }
    }
    __syncthreads();
    int cc = (sc < CAP) ? sc : CAP;
    if (tid == 0) sb0 = atomicAdd(&meta[n * MSTR + 4], cc);   // ONE global atomic per block
    __syncthreads();
    for (int i = tid; i < cc; i += 256) {
        int g = sb0 + i;
        if (g < CAP) kk[g] = sb[i];
    }
}

// ---------------- pass 3 (fallback): gated full-tensor compaction ----------------
__global__ __launch_bounds__(256) void k_compact_full(const float* __restrict__ bcls,
                                                      const float* __restrict__ sct,
                                                      int* __restrict__ meta,
                                                      uint64_t* __restrict__ keys) {
    __shared__ uint64_t sb[CAP];
    __shared__ int sc, sb0;
    const int c = blockIdx.x, n = blockIdx.y;
    const int tid = threadIdx.x;
    const int b1 = meta[n * MSTR + 0], b2 = meta[n * MSTR + 2];
    const float4* row = (const float4*)(bcls + ((size_t)n * NCLS + c) * HW);
    const float4* sr  = (const float4*)(sct + (size_t)n * HW);
    uint64_t* kk = keys + (size_t)n * CAP;
    if (tid == 0) sc = 0;
    __syncthreads();
    for (int v = tid; v < HW4; v += 256) {
        float4 x = row[v];
        if (x.x > GATE || x.y > GATE || x.z > GATE || x.w > GATE) {
            float4 t = sr[v];
            float xs[4] = {x.x, x.y, x.z, x.w};
            float ts[4] = {t.x, t.y, t.z, t.w};
            #pragma unroll
            for (int k = 0; k < 4; ++k) {
                if (xs[k] > GATE) {
                    float cl = sigf(xs[k]);
                    if (cl > PRE_TH) {
                        uint32_t u = __float_as_uint(cl * ts[k]);
                        int e1 = (int)(u >> 19);
                        int e2 = (int)((u >> 6) & (L2B - 1));
                        if (e1 > b1 || (e1 == b1 && e2 >= b2)) {
                            uint32_t f = (uint32_t)((4 * v + k) * NCLS + c);
                            uint64_t rec = ((uint64_t)u << 32) | (uint64_t)(0xFFFFFFFFu - f);
                            int pos = atomicAdd(&sc, 1);
                            if (pos < CAP) sb[pos] = rec;
                        }
                    }
                }
            }
        }
    }
    __syncthreads();
    int cc = (sc < CAP) ? sc : CAP;
    if (tid == 0) sb0 = atomicAdd(&meta[n * MSTR + 4], cc);
    __syncthreads();
    for (int i = tid; i < cc; i += 256) {
        int g = sb0 + i;
        if (g < CAP) kk[g] = sb[i];
    }
}

// ---------------- pass 4: rank-select + decode, sliced across 8 blocks/image ----------------
__global__ __launch_bounds__(256) void k_rankdec(const uint64_t* __restrict__ keys,
                                                 const int* __restrict__ meta,
                                                 const float* __restrict__ loc,
                                                 const float* __restrict__ breg,
                                                 const int* __restrict__ imsz,
                                                 float* __restrict__ dec) {
    __shared__ uint64_t sk[CAP];            // 16KB: full key set per block
    const int n = blockIdx.y;
    const int g = blockIdx.x;               // slice 0..7
    const int tid = threadIdx.x;
    int cn = meta[n * MSTR + 4]; if (cn > CAP) cn = CAP;
    const uint64_t* kk = keys + (size_t)n * CAP;
    #pragma unroll
    for (int s = 0; s < CAP / 256; ++s) {
        int i = s * 256 + tid;
        sk[i] = (i < cn) ? kk[i] : 0ULL;
    }
    __syncthreads();
    const int slot = g * 256 + tid;
    const uint64_t key = (slot < cn) ? sk[slot] : 0ULL;
    int r = 0;
    for (int j = 0; j < cn; ++j) r += (sk[j] > key);   // unique keys -> unique ranks
    if (slot < cn && r < TOPK) {
        uint32_t f = 0xFFFFFFFFu - (uint32_t)(key & 0xFFFFFFFFu);
        float sc = __uint_as_float((uint32_t)(key >> 32));
        int hw = (int)(f / NCLS);
        int c  = (int)(f % NCLS);
        float px = loc[2 * hw], py = loc[2 * hw + 1];
        const float* rg = breg + (size_t)n * 4 * HW;
        float l = rg[hw], t = rg[HW + hw], rr = rg[2 * HW + hw], b = rg[3 * HW + hw];
        float wm = (float)imsz[n * 2 + 1] - 1.0f;
        float hm = (float)imsz[n * 2 + 0] - 1.0f;
        float x1 = fminf(fmaxf(px - l, 0.0f), wm);
        float y1 = fminf(fmaxf(py - t, 0.0f), hm);
        float x2 = fminf(fmaxf(px + rr, 0.0f), wm);
        float y2 = fminf(fmaxf(py + b, 0.0f), hm);
        const int base = n * MROW + r;
        dec[0 * N_IMG * MROW + base] = x1;
        dec[1 * N_IMG * MROW + base] = y1;
        dec[2 * N_IMG * MROW + base] = x2;
        dec[3 * N_IMG * MROW + base] = y2;
        dec[4 * N_IMG * MROW + base] = sc;
        dec[5 * N_IMG * MROW + base] = (float)(c + 1);
    }
}

// ---------------- pass 5: parallel suppression-mask matrix (256 thr/blk) ----------------
__global__ __launch_bounds__(256) void k_mask(const float* __restrict__ dec,
                                              uint64_t* __restrict__ mask) {
    __shared__ float jx1[64], jy1[64], jx2[64], jy2[64];
    const int n  = blockIdx.z;
    const int jt = blockIdx.y;
    const int t  = threadIdx.x;
    const int i  = blockIdx.x * 256 + t;
    if (t < 64) {
        const int jb = n * MROW + jt * 64 + t;
        float off = dec[5 * N_IMG * MROW + jb] * CLS_OFF;
        jx1[t] = dec[0 * N_IMG * MROW + jb] + off;
        jy1[t] = dec[1 * N_IMG * MROW + jb] + off;
        jx2[t] = dec[2 * N_IMG * MROW + jb] + off;
        jy2[t] = dec[3 * N_IMG * MROW + jb] + off;
    }
    __syncthreads();
    const int ib = n * MROW + i;
    float offi = dec[5 * N_IMG * MROW + ib] * CLS_OFF;
    float ax1 = dec[0 * N_IMG * MROW + ib] + offi;
    float ay1 = dec[1 * N_IMG * MROW + ib] + offi;
    float ax2 = dec[2 * N_IMG * MROW + ib] + offi;
    float ay2 = dec[3 * N_IMG * MROW + ib] + offi;
    float aarea = fmaxf(ax2 - ax1, 0.0f) * fmaxf(ay2 - ay1, 0.0f);
    uint64_t bits = 0;
    #pragma unroll 8
    for (int jj = 0; jj < 64; ++jj) {
        float ix1 = fmaxf(ax1, jx1[jj]), iy1 = fmaxf(ay1, jy1[jj]);
        float ix2 = fminf(ax2, jx2[jj]), iy2 = fminf(ay2, jy2[jj]);
        float inter = fmaxf(ix2 - ix1, 0.0f) * fmaxf(iy2 - iy1, 0.0f);
        float barea = fmaxf(jx2[jj] - jx1[jj], 0.0f) * fmaxf(jy2[jj] - jy1[jj], 0.0f);
        float iou = inter / (aarea + barea - inter + 1e-9f);
        bits |= ((uint64_t)(!(iou <= NMS_TH))) << jj;
    }
    mask[(size_t)(n * MROW + i) * 16 + jt] = bits;
}

// ---------------- pass 6: greedy scan, address-static prefetch; writes full output ----------------
__global__ __launch_bounds__(64) void k_scan(const uint64_t* __restrict__ mask,
                                             const int* __restrict__ meta,
                                             const float* __restrict__ dec,
                                             float* __restrict__ out) {
    __shared__ uint64_t lrow[2][64 * 16];   // 2 x 8KB: double-buffered 64 mask rows
    __shared__ int keep[KEEP];
    const int n = blockIdx.x;
    const int lane = threadIdx.x;
    int cn = meta[n * MSTR + 4]; if (cn > CAP) cn = CAP;
    const int M = (cn < TOPK) ? cn : TOPK;
    const int nblk = (M + 63) >> 6;
    const uint64_t* mk = mask + (size_t)n * MROW * 16;

    const int r_off = lane >> 4;            // sub-row 0..3 within a 4-row load group
    const int w_off = lane & 15;            // word 0..15

    // preload block 0 (rows 0..63) into lrow[0]
    if (nblk > 0) {
        uint64_t v0[16];
        #pragma unroll
        for (int s = 0; s < 16; ++s)
            v0[s] = mk[(size_t)((s * 4 + r_off) * 16 + w_off)];
        #pragma unroll
        for (int s = 0; s < 16; ++s)
            lrow[0][(s * 4 + r_off) * 16 + w_off] = v0[s];
    }

    uint64_t rv = 0;                        // lanes 0..15 hold suppression words 0..15
    int kc = 0;
    for (int W = 0; W < nblk; ++W) {
        const int cb = W & 1;
        // prefetch next block global->regs (address-static: independent of decisions)
        uint64_t nx[16];
        if (W + 1 < nblk) {
            #pragma unroll
            for (int s = 0; s < 16; ++s)
                nx[s] = mk[(size_t)(((W + 1) * 64 + s * 4 + r_off) * 16 + w_off)];
        }
        // process block W: bit-scan over the 64 candidates of word W
        const int limit = M - W * 64;
        const uint64_t lm = (limit >= 64) ? ~0ull : ((1ull << limit) - 1ull);
        uint64_t v = __shfl(rv, W, 64);
        uint64_t u = (~v) & lm;
        while (u) {
            const int j = __builtin_ctzll(u);
            if (lane == 0) keep[kc] = W * 64 + j;
            ++kc;                                          // uniform
            if (kc == KEEP) break;
            uint64_t roww = lrow[cb][(size_t)j * 16 + w_off];   // row j, word (lane&15)
            rv |= roww;                                    // lanes 0..15 meaningful
            v = __shfl(rv, W, 64);
            const uint64_t hi = (j == 63) ? 0ull : ~((2ull << j) - 1ull);
            u = (~v) & lm & hi;
        }
        if (kc == KEEP) break;
        // stage prefetched rows into the other LDS buffer
        if (W + 1 < nblk) {
            #pragma unroll
            for (int s = 0; s < 16; ++s)
                lrow[cb ^ 1][(s * 4 + r_off) * 16 + w_off] = nx[s];
        }
    }

    // parallel output: gather kept rows, zero the rest (covers harness 0xAA poison)
    for (int idx = lane; idx < KEEP * 6; idx += 64) {
        int k = idx / 6, a = idx % 6;
        float vv = 0.0f;
        if (k < kc) vv = dec[a * N_IMG * MROW + n * MROW + keep[k]];
        out[(size_t)n * KEEP * 6 + idx] = vv;
    }
}

// ---------------- launch ----------------
extern "C" void kernel_launch(void* const* d_in, const int* in_sizes, int n_in,
                              void* d_out, int out_size, void* d_ws, size_t ws_size,
                              hipStream_t stream) {
    const float* loc  = (const float*)d_in[0];
    const float* bcls = (const float*)d_in[1];
    const float* breg = (const float*)d_in[2];
    const float* bctr = (const float*)d_in[3];
    const int*   imsz = (const int*)d_in[4];
    float* out = (float*)d_out;

    uint8_t* ws = (uint8_t*)d_ws;
    uint32_t* h1   = (uint32_t*)(ws);                  // 128KB            @0
    uint32_t* h2   = (uint32_t*)(ws + 131072);         // 256KB            @131072
    int*      meta = (int*)(ws + 393216);              // 512B (8×16 int)  @393216
    float*    sct  = (float*)(ws + 393728);            // 320000B          @393728
    uint64_t* keys = (uint64_t*)(ws + 713728);         // 8*2048*8=128KB   @713728
    float*    dec  = (float*)(ws + 844800);            // 192KB            @844800
    uint64_t* mask = (uint64_t*)(ws + 1041408);        // 1MB              @1041408
    uint64_t* cand = (uint64_t*)(ws + 2089984);        // 8MB (BIG only)   @2089984
    const bool big = ws_size >= 10478592;

    k_prep<<<(N_IMG * HW + 255) / 256, 256, 0, stream>>>(bctr, sct, h1, h2, meta);
    if (big) k_select<true> <<<dim3(NCLS, N_IMG), 256, 0, stream>>>(bcls, sct, h1, meta, cand);
    else     k_select<false><<<dim3(NCLS, N_IMG), 256, 0, stream>>>(bcls, sct, h1, meta, cand);
    k_scan1<<<N_IMG, 256, 0, stream>>>(h1, meta);
    if (big) k_refine_cand<<<dim3(32, N_IMG), 256, 0, stream>>>(cand, meta, h2);
    else     k_refine_full<<<dim3(NCLS, N_IMG), 256, 0, stream>>>(bcls, sct, meta, h2);
    k_scan2<<<N_IMG, 256, 0, stream>>>(h2, meta);
    if (big) k_compact_cand<<<dim3(32, N_IMG), 256, 0, stream>>>(cand, meta, keys);
    else     k_compact_full<<<dim3(NCLS, N_IMG), 256, 0, stream>>>(bcls, sct, meta, keys);
    k_rankdec<<<dim3(CAP / 256, N_IMG), 256, 0, stream>>>(keys, meta, loc, breg, imsz, dec);
    k_mask<<<dim3(MROW / 256, 16, N_IMG), 256, 0, stream>>>(dec, mask);
    k_scan<<<N_IMG, 64, 0, stream>>>(mask, meta, dec, out);
}

// Round 11
// 173.458 us; speedup vs baseline: 1.0123x; 1.0123x over previous
//
#include <hip/hip_runtime.h>
#include <stdint.h>

#define N_IMG 8
#define NCLS  80
#define HW    10000
#define HW4   (HW/4)
#define PER   (NCLS*HW)      /* 800000 per image */
#define L1B   4096           /* level-1 buckets: score bits 30:19 */
#define L2B   8192           /* level-2 buckets: score bits 18:6  */
#define TOPK  1000
#define CAP   2048           /* superset cap (skip-refine path guarantees <= CAP) */
#define KEEP  100
#define MROW  1024
#define CCAP  131072         /* candidate buffer cap per image (~117k expected) */
#define SCAP  4096           /* per-block LDS candidate staging cap (~1456 expected) */
#define GATE  (-3.0f)        /* sigmoid(-3.0)=0.04743 < 0.05: safe pre-gate */
#define PRE_TH 0.05f
#define NMS_TH 0.6f
#define CLS_OFF 4096.0f

/* meta layout: one 64B line per image, meta[n*16 + k]:
   k=0 B1, k=1 need, k=2 B2, k=3 cnt1, k=4 cnt2, k=5 skip_refine_flag */
#define MSTR 16

/* fast sigmoid: ~2-4 ulp vs libm. Used consistently for ALL score computation,
   so bucket boundaries / counts stay internally coherent. Decision safety:
   top-1000 spacing (~4e-4) and NMS-relevant gaps >> 4 ulp; cl~0.05 boundary
   candidates provably can't reach top-1000 (score <= 0.0495 < cutoff > 0.05). */
__device__ __forceinline__ float sigf(float x) {
    return __fdividef(1.0f, 1.0f + __expf(-x));
}

// ---------------- pass 0: sigmoid(centerness) + zero hists/meta (replaces memset) ----------------
__global__ __launch_bounds__(256) void k_prep(const float* __restrict__ bctr,
                                              float* __restrict__ sct,
                                              uint32_t* __restrict__ h1,
                                              uint32_t* __restrict__ h2,
                                              int* __restrict__ meta) {
    const int gid = blockIdx.x * 256 + threadIdx.x;
    const int gsz = gridDim.x * 256;
    for (int i = gid; i < N_IMG * HW; i += gsz) sct[i] = sigf(bctr[i]);
    for (int i = gid; i < N_IMG * L1B; i += gsz) h1[i] = 0;
    for (int i = gid; i < N_IMG * L2B; i += gsz) h2[i] = 0;
    if (gid < N_IMG * MSTR) meta[gid] = 0;
}

// ---------------- pass 1: gated select — LDS histogram + LDS-staged compaction ----------------
template<bool BIG>
__global__ __launch_bounds__(256) void k_select(const float* __restrict__ bcls,
                                                const float* __restrict__ sct,
                                                uint32_t* __restrict__ h1,
                                                int* __restrict__ meta,
                                                uint64_t* __restrict__ cand) {
    __shared__ uint32_t h[L1B];      // 16KB LDS histogram
    __shared__ uint64_t sbuf[SCAP];  // 32KB LDS candidate staging
    __shared__ int scnt, sbase;
    const int c = blockIdx.x, n = blockIdx.y;
    const int tid = threadIdx.x;
    for (int b = tid; b < L1B; b += 256) h[b] = 0;
    if (tid == 0) scnt = 0;
    __syncthreads();

    const float4* row = (const float4*)(bcls + ((size_t)n * NCLS + c) * HW);
    const float4* sr  = (const float4*)(sct + (size_t)n * HW);
    uint64_t* cb = cand + (size_t)n * CCAP;
    int* cnt1 = &meta[n * MSTR + 3];
    for (int v = tid; v < HW4; v += 256) {
        float4 x = row[v];
        if (x.x > GATE || x.y > GATE || x.z > GATE || x.w > GATE) {
            float4 t = sr[v];
            float xs[4] = {x.x, x.y, x.z, x.w};
            float ts[4] = {t.x, t.y, t.z, t.w};
            #pragma unroll
            for (int k = 0; k < 4; ++k) {
                if (xs[k] > GATE) {
                    float cl = sigf(xs[k]);
                    if (cl > PRE_TH) {
                        uint32_t u = __float_as_uint(cl * ts[k]);
                        atomicAdd(&h[u >> 19], 1u);                   // LDS atomic
                        if (BIG) {
                            uint32_t f = (uint32_t)((4 * v + k) * NCLS + c);
                            uint64_t rec = ((uint64_t)u << 32) | (uint64_t)(0xFFFFFFFFu - f);
                            int pos = atomicAdd(&scnt, 1);            // LDS atomic
                            if (pos < SCAP) sbuf[pos] = rec;
                            else {                                    // statistical overflow path
                                int g = atomicAdd(cnt1, 1);
                                if (g < CCAP) cb[g] = rec;
                            }
                        }
                    }
                }
            }
        }
    }
    __syncthreads();

    // merge LDS histogram (sparse: ~160 nonzero buckets)
    uint32_t* gh = h1 + n * L1B;
    for (int b = tid; b < L1B; b += 256)
        if (h[b]) atomicAdd(&gh[b], h[b]);

    // bulk-reserve one chunk per block, coalesced flush
    if (BIG) {
        int cc = (scnt < SCAP) ? scnt : SCAP;
        if (tid == 0) sbase = atomicAdd(cnt1, cc);
        __syncthreads();
        for (int i = tid; i < cc; i += 256) {
            int g = sbase + i;
            if (g < CCAP) cb[g] = sbuf[i];
        }
    }
}

// ---------------- scan 1: level-1 boundary bucket + skip-refine decision ----------------
__global__ __launch_bounds__(256) void k_scan1(const uint32_t* __restrict__ hist,
                                               int* __restrict__ meta) {
    __shared__ uint32_t csum[256];
    const int n = blockIdx.x;
    const uint32_t* h = hist + n * L1B;
    const int t = threadIdx.x;
    uint32_t s = 0;
    for (int b = t * 16; b < t * 16 + 16; ++b) s += h[b];
    csum[t] = s;
    __syncthreads();
    if (t == 0) {
        long long acc = 0;
        int b1 = -1;
        for (int c = 255; c >= 0; --c) {
            if (acc + (long long)csum[c] >= TOPK) {
                for (int b = c * 16 + 15; b >= c * 16; --b) {
                    if (acc + (long long)h[b] >= TOPK) { b1 = b; break; }
                    acc += h[b];
                }
                break;
            }
            acc += csum[c];
        }
        int flag, nee;
        if (b1 < 0) {                       // fewer than TOPK candidates: take all
            b1 = 0; nee = 0; flag = 1;
        } else {
            nee = TOPK - (int)acc;
            flag = (acc + (long long)h[b1] <= CAP) ? 1 : 0;   // superset fits: skip L2 refine
        }
        meta[n * MSTR + 0] = b1;
        meta[n * MSTR + 1] = nee;
        if (flag) meta[n * MSTR + 2] = 0;   // B2 = 0 -> take whole boundary bucket
        meta[n * MSTR + 5] = flag;
    }
}

// ---------------- pass 2 (candbuf): L2 histogram inside boundary bucket ----------------
__global__ __launch_bounds__(256) void k_refine_cand(const uint64_t* __restrict__ cand,
                                                     const int* __restrict__ meta,
                                                     uint32_t* __restrict__ h2) {
    const int n = blockIdx.y;
    if (meta[n * MSTR + 5]) return;         // skip-refine fast path
    int cn = meta[n * MSTR + 3]; if (cn > CCAP) cn = CCAP;
    const int b1 = meta[n * MSTR + 0];
    const uint64_t* cb = cand + (size_t)n * CCAP;
    uint32_t* h = h2 + n * L2B;
    const int stride = gridDim.x * blockDim.x;
    for (int i = blockIdx.x * blockDim.x + threadIdx.x; i < cn; i += stride) {
        uint32_t u = (uint32_t)(cb[i] >> 32);
        if ((int)(u >> 19) == b1) atomicAdd(&h[(u >> 6) & (L2B - 1)], 1u);
    }
}

// ---------------- pass 2 (fallback): gated full-tensor L2 histogram ----------------
__global__ __launch_bounds__(256) void k_refine_full(const float* __restrict__ bcls,
                                                     const float* __restrict__ sct,
                                                     const int* __restrict__ meta,
                                                     uint32_t* __restrict__ h2) {
    const int c = blockIdx.x, n = blockIdx.y;
    if (meta[n * MSTR + 5]) return;         // skip-refine fast path
    const int b1 = meta[n * MSTR + 0];
    const float4* row = (const float4*)(bcls + ((size_t)n * NCLS + c) * HW);
    const float4* sr  = (const float4*)(sct + (size_t)n * HW);
    uint32_t* h = h2 + n * L2B;
    for (int v = threadIdx.x; v < HW4; v += 256) {
        float4 x = row[v];
        if (x.x > GATE || x.y > GATE || x.z > GATE || x.w > GATE) {
            float4 t = sr[v];
            float xs[4] = {x.x, x.y, x.z, x.w};
            float ts[4] = {t.x, t.y, t.z, t.w};
            #pragma unroll
            for (int k = 0; k < 4; ++k) {
                if (xs[k] > GATE) {
                    float cl = sigf(xs[k]);
                    if (cl > PRE_TH) {
                        uint32_t u = __float_as_uint(cl * ts[k]);
                        if ((int)(u >> 19) == b1)
                            atomicAdd(&h[(u >> 6) & (L2B - 1)], 1u);
                    }
                }
            }
        }
    }
}

// ---------------- scan 2: level-2 boundary sub-bucket ----------------
__global__ __launch_bounds__(256) void k_scan2(const uint32_t* __restrict__ hist2,
                                               int* __restrict__ meta) {
    __shared__ uint32_t csum[256];
    const int n = blockIdx.x;
    if (meta[n * MSTR + 5]) return;         // skip-refine fast path (B2 stays 0 / unused)
    const uint32_t* h = hist2 + n * L2B;
    const long long target = meta[n * MSTR + 1];
    const int t = threadIdx.x;
    uint32_t s = 0;
    for (int b = t * 32; b < t * 32 + 32; ++b) s += h[b];
    csum[t] = s;
    __syncthreads();
    if (t == 0) {
        long long acc = 0;
        int b2 = 0;
        bool found = false;
        for (int c = 255; c >= 0 && !found; --c) {
            if (acc + (long long)csum[c] >= target) {
                for (int b = c * 32 + 31; b >= c * 32; --b) {
                    if (acc + (long long)h[b] >= target) { b2 = b; found = true; break; }
                    acc += h[b];
                }
            } else {
                acc += csum[c];
            }
        }
        meta[n * MSTR + 2] = b2;
    }
}

// ---------------- pass 3 (candbuf): final compaction, LDS-staged ----------------
__global__ __launch_bounds__(256) void k_compact_cand(const uint64_t* __restrict__ cand,
                                                      int* __restrict__ meta,
                                                      uint64_t* __restrict__ keys) {
    __shared__ uint64_t sb[CAP];            // 16KB winner staging
    __shared__ int sc, sb0;
    const int n = blockIdx.y;
    const int tid = threadIdx.x;
    int cn = meta[n * MSTR + 3]; if (cn > CCAP) cn = CCAP;
    const int b1 = meta[n * MSTR + 0], b2 = meta[n * MSTR + 2];
    const uint64_t* cb = cand + (size_t)n * CCAP;
    uint64_t* kk = keys + (size_t)n * CAP;
    if (tid == 0) sc = 0;
    __syncthreads();
    const int stride = gridDim.x * blockDim.x;
    for (int i = blockIdx.x * blockDim.x + tid; i < cn; i += stride) {
        uint64_t rec = cb[i];
        uint32_t u = (uint32_t)(rec >> 32);
        int e1 = (int)(u >> 19);
        int e2 = (int)((u >> 6) & (L2B - 1));
        if (e1 > b1 || (e1 == b1 && e2 >= b2)) {
            int pos = atomicAdd(&sc, 1);    // LDS atomic
            if (pos < CAP) sb[pos] = rec;
        }
    }
    __syncthreads();
    int cc = (sc < CAP) ? sc : CAP;
    if (tid == 0) sb0 = atomicAdd(&meta[n * MSTR + 4], cc);   // ONE global atomic per block
    __syncthreads();
    for (int i = tid; i < cc; i += 256) {
        int g = sb0 + i;
        if (g < CAP) kk[g] = sb[i];
    }
}

// ---------------- pass 3 (fallback): gated full-tensor compaction ----------------
__global__ __launch_bounds__(256) void k_compact_full(const float* __restrict__ bcls,
                                                      const float* __restrict__ sct,
                                                      int* __restrict__ meta,
                                                      uint64_t* __restrict__ keys) {
    __shared__ uint64_t sb[CAP];
    __shared__ int sc, sb0;
    const int c = blockIdx.x, n = blockIdx.y;
    const int tid = threadIdx.x;
    const int b1 = meta[n * MSTR + 0], b2 = meta[n * MSTR + 2];
    const float4* row = (const float4*)(bcls + ((size_t)n * NCLS + c) * HW);
    const float4* sr  = (const float4*)(sct + (size_t)n * HW);
    uint64_t* kk = keys + (size_t)n * CAP;
    if (tid == 0) sc = 0;
    __syncthreads();
    for (int v = tid; v < HW4; v += 256) {
        float4 x = row[v];
        if (x.x > GATE || x.y > GATE || x.z > GATE || x.w > GATE) {
            float4 t = sr[v];
            float xs[4] = {x.x, x.y, x.z, x.w};
            float ts[4] = {t.x, t.y, t.z, t.w};
            #pragma unroll
            for (int k = 0; k < 4; ++k) {
                if (xs[k] > GATE) {
                    float cl = sigf(xs[k]);
                    if (cl > PRE_TH) {
                        uint32_t u = __float_as_uint(cl * ts[k]);
                        int e1 = (int)(u >> 19);
                        int e2 = (int)((u >> 6) & (L2B - 1));
                        if (e1 > b1 || (e1 == b1 && e2 >= b2)) {
                            uint32_t f = (uint32_t)((4 * v + k) * NCLS + c);
                            uint64_t rec = ((uint64_t)u << 32) | (uint64_t)(0xFFFFFFFFu - f);
                            int pos = atomicAdd(&sc, 1);
                            if (pos < CAP) sb[pos] = rec;
                        }
                    }
                }
            }
        }
    }
    __syncthreads();
    int cc = (sc < CAP) ? sc : CAP;
    if (tid == 0) sb0 = atomicAdd(&meta[n * MSTR + 4], cc);
    __syncthreads();
    for (int i = tid; i < cc; i += 256) {
        int g = sb0 + i;
        if (g < CAP) kk[g] = sb[i];
    }
}

// ---------------- pass 4: rank-select + decode, sliced across 8 blocks/image ----------------
__global__ __launch_bounds__(256) void k_rankdec(const uint64_t* __restrict__ keys,
                                                 const int* __restrict__ meta,
                                                 const float* __restrict__ loc,
                                                 const float* __restrict__ breg,
                                                 const int* __restrict__ imsz,
                                                 float* __restrict__ dec) {
    __shared__ uint64_t sk[CAP];            // 16KB: full key set per block
    const int n = blockIdx.y;
    const int g = blockIdx.x;               // slice 0..7
    const int tid = threadIdx.x;
    int cn = meta[n * MSTR + 4]; if (cn > CAP) cn = CAP;
    const uint64_t* kk = keys + (size_t)n * CAP;
    #pragma unroll
    for (int s = 0; s < CAP / 256; ++s) {
        int i = s * 256 + tid;
        sk[i] = (i < cn) ? kk[i] : 0ULL;
    }
    __syncthreads();
    const int slot = g * 256 + tid;
    const uint64_t key = (slot < cn) ? sk[slot] : 0ULL;
    int r = 0;
    for (int j = 0; j < cn; ++j) r += (sk[j] > key);   // unique keys -> unique ranks
    if (slot < cn && r < TOPK) {
        uint32_t f = 0xFFFFFFFFu - (uint32_t)(key & 0xFFFFFFFFu);
        float sc = __uint_as_float((uint32_t)(key >> 32));
        int hw = (int)(f / NCLS);
        int c  = (int)(f % NCLS);
        float px = loc[2 * hw], py = loc[2 * hw + 1];
        const float* rg = breg + (size_t)n * 4 * HW;
        float l = rg[hw], t = rg[HW + hw], rr = rg[2 * HW + hw], b = rg[3 * HW + hw];
        float wm = (float)imsz[n * 2 + 1] - 1.0f;
        float hm = (float)imsz[n * 2 + 0] - 1.0f;
        float x1 = fminf(fmaxf(px - l, 0.0f), wm);
        float y1 = fminf(fmaxf(py - t, 0.0f), hm);
        float x2 = fminf(fmaxf(px + rr, 0.0f), wm);
        float y2 = fminf(fmaxf(py + b, 0.0f), hm);
        const int base = n * MROW + r;
        dec[0 * N_IMG * MROW + base] = x1;
        dec[1 * N_IMG * MROW + base] = y1;
        dec[2 * N_IMG * MROW + base] = x2;
        dec[3 * N_IMG * MROW + base] = y2;
        dec[4 * N_IMG * MROW + base] = sc;
        dec[5 * N_IMG * MROW + base] = (float)(c + 1);
    }
}

// ---------------- pass 5: parallel suppression-mask matrix (256 thr/blk) ----------------
__global__ __launch_bounds__(256) void k_mask(const float* __restrict__ dec,
                                              uint64_t* __restrict__ mask) {
    __shared__ float jx1[64], jy1[64], jx2[64], jy2[64];
    const int n  = blockIdx.z;
    const int jt = blockIdx.y;
    const int t  = threadIdx.x;
    const int i  = blockIdx.x * 256 + t;
    if (t < 64) {
        const int jb = n * MROW + jt * 64 + t;
        float off = dec[5 * N_IMG * MROW + jb] * CLS_OFF;
        jx1[t] = dec[0 * N_IMG * MROW + jb] + off;
        jy1[t] = dec[1 * N_IMG * MROW + jb] + off;
        jx2[t] = dec[2 * N_IMG * MROW + jb] + off;
        jy2[t] = dec[3 * N_IMG * MROW + jb] + off;
    }
    __syncthreads();
    const int ib = n * MROW + i;
    float offi = dec[5 * N_IMG * MROW + ib] * CLS_OFF;
    float ax1 = dec[0 * N_IMG * MROW + ib] + offi;
    float ay1 = dec[1 * N_IMG * MROW + ib] + offi;
    float ax2 = dec[2 * N_IMG * MROW + ib] + offi;
    float ay2 = dec[3 * N_IMG * MROW + ib] + offi;
    float aarea = fmaxf(ax2 - ax1, 0.0f) * fmaxf(ay2 - ay1, 0.0f);
    uint64_t bits = 0;
    #pragma unroll 8
    for (int jj = 0; jj < 64; ++jj) {
        float ix1 = fmaxf(ax1, jx1[jj]), iy1 = fmaxf(ay1, jy1[jj]);
        float ix2 = fminf(ax2, jx2[jj]), iy2 = fminf(ay2, jy2[jj]);
        float inter = fmaxf(ix2 - ix1, 0.0f) * fmaxf(iy2 - iy1, 0.0f);
        float barea = fmaxf(jx2[jj] - jx1[jj], 0.0f) * fmaxf(jy2[jj] - jy1[jj], 0.0f);
        float iou = inter / (aarea + barea - inter + 1e-9f);
        bits |= ((uint64_t)(!(iou <= NMS_TH))) << jj;
    }
    mask[(size_t)(n * MROW + i) * 16 + jt] = bits;
}

// ---------------- pass 6: greedy scan — register diagonal + batched row-OR ----------------
__global__ __launch_bounds__(64) void k_scan(const uint64_t* __restrict__ mask,
                                             const int* __restrict__ meta,
                                             const float* __restrict__ dec,
                                             float* __restrict__ out) {
    __shared__ uint64_t lrow[2][64 * 17];   // padded rows: row r word w at [r*17+w]
    __shared__ int keep[KEEP];
    const int n = blockIdx.x;
    const int lane = threadIdx.x;
    int cn = meta[n * MSTR + 4]; if (cn > CAP) cn = CAP;
    const int M = (cn < TOPK) ? cn : TOPK;
    const int nblk = (M + 63) >> 6;
    const uint64_t* mk = mask + (size_t)n * MROW * 16;

    const int r_off = lane >> 4;            // sub-row 0..3 within a 4-row load group
    const int w_off = lane & 15;            // word 0..15

    // preload block 0 (rows 0..63) into lrow[0]
    if (nblk > 0) {
        #pragma unroll
        for (int s = 0; s < 16; ++s) {
            uint64_t v0 = mk[(size_t)((s * 4 + r_off) * 16 + w_off)];
            lrow[0][(s * 4 + r_off) * 17 + w_off] = v0;
        }
    }

    uint64_t rv = 0;                        // lanes 0..15 hold suppression words 0..15
    int kc = 0;
    for (int W = 0; W < nblk && kc < KEEP; ++W) {
        const int cb = W & 1;
        // prefetch next block global->regs (address-static: independent of decisions)
        uint64_t nx[16];
        if (W + 1 < nblk) {
            #pragma unroll
            for (int s = 0; s < 16; ++s)
                nx[s] = mk[(size_t)(((W + 1) * 64 + s * 4 + r_off) * 16 + w_off)];
        }
        // diagonal into registers: lane l holds word W of row (W*64 + l)
        uint64_t diag = lrow[cb][lane * 17 + W];

        // process block W: intra-block suppression via register shuffles only
        const int limit = M - W * 64;
        const uint64_t lm = (limit >= 64) ? ~0ull : ((1ull << limit) - 1ull);
        uint64_t sup = __shfl(rv, W, 64);   // static cross-block suppression word
        uint64_t kmask = 0;
        uint64_t u = (~sup) & lm;
        while (u) {
            const int j = __builtin_ctzll(u);
            if (lane == 0) keep[kc] = W * 64 + j;
            kmask |= (1ull << j);
            ++kc;                                          // uniform
            if (kc == KEEP) break;
            sup |= __shfl(diag, j, 64);                    // row j's word W (register)
            const uint64_t hi = (j == 63) ? 0ull : ~((2ull << j) - 1ull);
            u = (~sup) & lm & hi;
        }
        // batch-OR kept rows' full words into rv (independent LDS loads, pipelined)
        uint64_t km = kmask;
        while (km) {
            const int j = __builtin_ctzll(km); km &= km - 1;
            rv |= lrow[cb][j * 17 + w_off];                // lanes 0..15 meaningful
        }
        // stage prefetched rows into the other LDS buffer
        if (W + 1 < nblk) {
            #pragma unroll
            for (int s = 0; s < 16; ++s)
                lrow[cb ^ 1][(s * 4 + r_off) * 17 + w_off] = nx[s];
        }
    }

    // parallel output: gather kept rows, zero the rest (covers harness 0xAA poison)
    for (int idx = lane; idx < KEEP * 6; idx += 64) {
        int k = idx / 6, a = idx % 6;
        float vv = 0.0f;
        if (k < kc) vv = dec[a * N_IMG * MROW + n * MROW + keep[k]];
        out[(size_t)n * KEEP * 6 + idx] = vv;
    }
}

// ---------------- launch ----------------
extern "C" void kernel_launch(void* const* d_in, const int* in_sizes, int n_in,
                              void* d_out, int out_size, void* d_ws, size_t ws_size,
                              hipStream_t stream) {
    const float* loc  = (const float*)d_in[0];
    const float* bcls = (const float*)d_in[1];
    const float* breg = (const float*)d_in[2];
    const float* bctr = (const float*)d_in[3];
    const int*   imsz = (const int*)d_in[4];
    float* out = (float*)d_out;

    uint8_t* ws = (uint8_t*)d_ws;
    uint32_t* h1   = (uint32_t*)(ws);                  // 128KB            @0
    uint32_t* h2   = (uint32_t*)(ws + 131072);         // 256KB            @131072
    int*      meta = (int*)(ws + 393216);              // 512B (8×16 int)  @393216
    float*    sct  = (float*)(ws + 393728);            // 320000B          @393728
    uint64_t* keys = (uint64_t*)(ws + 713728);         // 8*2048*8=128KB   @713728
    float*    dec  = (float*)(ws + 844800);            // 192KB            @844800
    uint64_t* mask = (uint64_t*)(ws + 1041408);        // 1MB              @1041408
    uint64_t* cand = (uint64_t*)(ws + 2089984);        // 8MB (BIG only)   @2089984
    const bool big = ws_size >= 10478592;

    k_prep<<<(N_IMG * HW + 255) / 256, 256, 0, stream>>>(bctr, sct, h1, h2, meta);
    if (big) k_select<true> <<<dim3(NCLS, N_IMG), 256, 0, stream>>>(bcls, sct, h1, meta, cand);
    else     k_select<false><<<dim3(NCLS, N_IMG), 256, 0, stream>>>(bcls, sct, h1, meta, cand);
    k_scan1<<<N_IMG, 256, 0, stream>>>(h1, meta);
    if (big) k_refine_cand<<<dim3(32, N_IMG), 256, 0, stream>>>(cand, meta, h2);
    else     k_refine_full<<<dim3(NCLS, N_IMG), 256, 0, stream>>>(bcls, sct, meta, h2);
    k_scan2<<<N_IMG, 256, 0, stream>>>(h2, meta);
    if (big) k_compact_cand<<<dim3(32, N_IMG), 256, 0, stream>>>(cand, meta, keys);
    else     k_compact_full<<<dim3(NCLS, N_IMG), 256, 0, stream>>>(bcls, sct, meta, keys);
    k_rankdec<<<dim3(CAP / 256, N_IMG), 256, 0, stream>>>(keys, meta, loc, breg, imsz, dec);
    k_mask<<<dim3(MROW / 256, 16, N_IMG), 256, 0, stream>>>(dec, mask);
    k_scan<<<N_IMG, 64, 0, stream>>>(mask, meta, dec, out);
}